// Round 3
// baseline (212.832 us; speedup 1.0000x reference)
//
#include <hip/hip_runtime.h>

typedef __attribute__((ext_vector_type(8))) short bf16x8;
typedef __attribute__((ext_vector_type(4))) float f32x4;
typedef unsigned int u32;
typedef unsigned short u16;

__device__ __forceinline__ u16 f2bf(float f) {
  u32 u = __float_as_uint(f);
  u += 0x7fffu + ((u >> 16) & 1u);   // RNE
  return (u16)(u >> 16);
}
__device__ __forceinline__ u32 pack2(float a, float b) {
  return (u32)f2bf(a) | ((u32)f2bf(b) << 16);
}
__device__ __forceinline__ void gload_lds16(const void* g, void* l) {
  __builtin_amdgcn_global_load_lds(
      (const __attribute__((address_space(1))) u32*)g,
      (__attribute__((address_space(3))) u32*)l, 16, 0, 0);
}

// ---------------- pre-pass: f32 -> bf16 (K, W) ----------------
__global__ void cvt_bf16_kernel(const float* __restrict__ in, u16* __restrict__ out,
                                long long n8) {
  long long i = (long long)blockIdx.x * blockDim.x + threadIdx.x;
  if (i >= n8) return;
  const float4* p = (const float4*)in + i * 2;
  float4 a = p[0], b = p[1];
  uint4 o;
  o.x = pack2(a.x, a.y); o.y = pack2(a.z, a.w);
  o.z = pack2(b.x, b.y); o.w = pack2(b.z, b.w);
  ((uint4*)out)[i] = o;
}

// ---------------- pre-pass: V[b][n][d] -> Vt[b][d][n] (bf16) ----------------
__global__ __launch_bounds__(256)
void transpose_v_kernel(const float* __restrict__ V, u16* __restrict__ Vt) {
  __shared__ float tile[64][65];
  const int n0 = blockIdx.x * 64, d0 = blockIdx.y * 64, bat = blockIdx.z;
  const int t = threadIdx.x;
  const int rr = t >> 4, cc = (t & 15) * 4;
#pragma unroll
  for (int i = 0; i < 4; ++i) {
    int r = i * 16 + rr;
    float4 v = *(const float4*)(V + ((size_t)(bat * 2048 + n0 + r)) * 512 + d0 + cc);
    tile[r][cc + 0] = v.x; tile[r][cc + 1] = v.y;
    tile[r][cc + 2] = v.z; tile[r][cc + 3] = v.w;
  }
  __syncthreads();
#pragma unroll
  for (int i = 0; i < 4; ++i) {
    int dr = i * 16 + rr;
    uint2 o;
    o.x = pack2(tile[cc + 0][dr], tile[cc + 1][dr]);
    o.y = pack2(tile[cc + 2][dr], tile[cc + 3][dr]);
    *(uint2*)(Vt + ((size_t)(bat * 512 + d0 + dr)) * 2048 + n0 + cc) = o;
  }
}

// ------- fused flash attention + projection (rotated pipeline):
//   R = relu(softmax(QK^T*s) @ V);  Out = a*R + b*relu((V-R) @ W^T)
// Per iter: loads -> QK^T -> partial-max(LDS pm) -> ONE barrier ->
//           { softmax-finish (in-reg m,l) || PV(it-1) }  (independent streams)
// LDS layout (bytes):
//  Ks0 [64][512] bf16 XOR-swz @0       (65536)  (Q scratch prologue; T=V-R epilogue)
//  Ks1 [64][512] bf16 XOR-swz @65536   (65536)
//  Ps  [2][64][128B] bf16 XOR-swz @131072 (16384)
//  pm  [2][64][2] f32          @147456  (1024)   (buf0 reused as l-halves at end)
//  resc[2][64] f32             @148480  (512)
//  flg [2][4] u32              @148992  (32)
#define ATT_LDS 149056

__global__ __launch_bounds__(512, 2)
void attn_kernel(const float* __restrict__ Qf, const u16* __restrict__ Kb,
                 const u16* __restrict__ Vtg, const float* __restrict__ Vg,
                 const u16* __restrict__ Wb, const float* __restrict__ sp,
                 const float* __restrict__ ap, const float* __restrict__ bp,
                 float* __restrict__ Out) {
  extern __shared__ char smem[];
  u16* Ks0 = (u16*)smem;
  u16* Ks1 = (u16*)(smem + 65536);
  char* PsB = smem + 131072;             // Ps[2], 8192 each
  float* pm = (float*)(smem + 147456);   // [2][128]
  float* resc = (float*)(smem + 148480); // [2][64]
  u32* flg = (u32*)(smem + 148992);      // [2][4]

  const int tid = threadIdx.x, lane = tid & 63, wid = tid >> 6;
  const int bat = blockIdx.x, q0 = blockIdx.y * 64;  // flat%8 == bat -> per-XCD batch locality
  const float scale = sp[0] * 0.04419417382415922f;  // 1/sqrt(512)
  const int l15 = lane & 15, l4 = lane >> 4;
  const int srow = tid >> 3, sseg = tid & 7;
  const int rwD = wid >> 1, cwD = wid & 1;  // QK^T wave tile: 16 q-rows x 32 kv-cols

  // ---- prologue: stage Q (pre-scaled) f32 -> bf16 swizzled into Ks0 scratch ----
  {
    const float* qsrc = Qf + ((size_t)(bat * 2048 + q0 + srow)) * 512;
    char* qdst = (char*)Ks0 + srow * 1024;
    const int sw = (srow & 7) << 4;
#pragma unroll
    for (int j = 0; j < 8; ++j) {
      int sc = sseg * 8 + j;
      float4 x0 = *(const float4*)(qsrc + sc * 8);
      float4 x1 = *(const float4*)(qsrc + sc * 8 + 4);
      uint4 w;
      w.x = pack2(x0.x * scale, x0.y * scale); w.y = pack2(x0.z * scale, x0.w * scale);
      w.z = pack2(x1.x * scale, x1.y * scale); w.w = pack2(x1.z * scale, x1.w * scale);
      *(uint4*)(qdst + ((sc * 16) ^ sw)) = w;
    }
  }
  __syncthreads();

  // ---- load persistent Q A-fragments (16 q-rows per wave -> qf = 64 VGPRs) ----
  bf16x8 qf[16];
  {
    const char* qb = (const char*)Ks0 + (rwD * 16 + l15) * 1024;
    const int swA = (l15 & 7) << 4;
#pragma unroll
    for (int ks = 0; ks < 16; ++ks)
      qf[ks] = *(const bf16x8*)(qb + ((ks * 64 + l4 * 16) ^ swA));
  }
  __syncthreads();  // frag reads done before K(0) overwrites Ks0 scratch

  // ---- stage K(0) via global_load_lds (source pre-swizzled per lane) ----
#pragma unroll
  for (int j = 0; j < 8; ++j) {
    int row = wid * 8 + j;
    gload_lds16(Kb + ((size_t)(bat * 2048 + row)) * 512 + ((lane ^ (row & 7)) * 8),
                (char*)Ks0 + row * 1024);
  }

  f32x4 o[4][4];
#pragma unroll
  for (int a = 0; a < 4; ++a)
#pragma unroll
    for (int b = 0; b < 4; ++b) o[a][b] = (f32x4){0.f, 0.f, 0.f, 0.f};

  // per-lane online-softmax state for rows rwD*16 + l4*4 + j (replicated over l15)
  float mreg[4], lreg[4];
#pragma unroll
  for (int j = 0; j < 4; ++j) { mreg[j] = -1e30f; lreg[j] = 0.f; }

  __syncthreads();  // K(0) resident + visible

  const int swB = (l15 & 7) << 4;

  for (int it = 0; it < 32; ++it) {
    const int b = it & 1;
    const u16* Kcur = b ? Ks1 : Ks0;
    u16* Knxt = b ? Ks0 : Ks1;

    // ---- [top] V(it-1) -> vregs for this iter's PV (cover = QK^T) ----
    uint4 vreg[8];
    if (it > 0) {
#pragma unroll
      for (int cf = 0; cf < 4; ++cf)
#pragma unroll
        for (int s = 0; s < 2; ++s)
          vreg[cf * 2 + s] = *(const uint4*)(Vtg +
              ((size_t)(bat * 512 + wid * 64 + cf * 16 + l15)) * 2048 +
              (it - 1) * 64 + s * 32 + l4 * 8);
    }
    // ---- [top] K(it+1) -> Ks[nxt] via gload_lds (cover = QK^T; drains at bar) ----
    if (it < 31) {
      const int kv1 = (it + 1) * 64;
#pragma unroll
      for (int j = 0; j < 8; ++j) {
        int row = wid * 8 + j;
        gload_lds16(Kb + ((size_t)(bat * 2048 + kv1 + row)) * 512 + ((lane ^ (row & 7)) * 8),
                    (char*)Knxt + row * 1024);
      }
    }
    __builtin_amdgcn_sched_barrier(0);  // pin all load issues above QK^T

    // ---- QK^T: wave = 16 q-rows x 32 kv-cols, K=512, 4 split acc chains ----
    f32x4 sp0 = (f32x4){0,0,0,0}, sp1 = (f32x4){0,0,0,0};
    f32x4 sp2 = (f32x4){0,0,0,0}, sp3 = (f32x4){0,0,0,0};
    {
      const char* kb0 = (const char*)Kcur + (cwD * 32 + l15) * 1024;
      const char* kb1 = kb0 + 16 * 1024;
#pragma unroll
      for (int ks = 0; ks < 16; ks += 2) {
        const int off0 = (ks * 64 + l4 * 16) ^ swB;
        const int off1 = ((ks + 1) * 64 + l4 * 16) ^ swB;
        bf16x8 b00 = *(const bf16x8*)(kb0 + off0);
        bf16x8 b10 = *(const bf16x8*)(kb1 + off0);
        bf16x8 b01 = *(const bf16x8*)(kb0 + off1);
        bf16x8 b11 = *(const bf16x8*)(kb1 + off1);
        sp0 = __builtin_amdgcn_mfma_f32_16x16x32_bf16(qf[ks], b00, sp0, 0, 0, 0);
        sp2 = __builtin_amdgcn_mfma_f32_16x16x32_bf16(qf[ks], b10, sp2, 0, 0, 0);
        sp1 = __builtin_amdgcn_mfma_f32_16x16x32_bf16(qf[ks + 1], b01, sp1, 0, 0, 0);
        sp3 = __builtin_amdgcn_mfma_f32_16x16x32_bf16(qf[ks + 1], b11, sp3, 0, 0, 0);
      }
    }
    f32x4 s0 = sp0 + sp1, s1 = sp2 + sp3;  // s0: cols cwD*32+l15; s1: +16; rows l4*4+j

    // ---- in-register partial row-max over this wave's 32 kv cols ----
    float mt[4];
#pragma unroll
    for (int j = 0; j < 4; ++j) mt[j] = fmaxf(s0[j], s1[j]);
#pragma unroll
    for (int off = 1; off < 16; off <<= 1)
#pragma unroll
      for (int j = 0; j < 4; ++j) mt[j] = fmaxf(mt[j], __shfl_xor(mt[j], off));
    if (l15 == 0) {
      float* pmb = pm + b * 128;
#pragma unroll
      for (int j = 0; j < 4; ++j) pmb[(rwD * 16 + l4 * 4 + j) * 2 + cwD] = mt[j];
    }

    __syncthreads();  // the ONLY barrier: pm visible; K(it+1)/V drained

    // ---- softmax-finish(it): in-reg m,l with defer-max (THR=8) ----
    {
      const float* pmb = pm + b * 128;
      float p0[4], p1[4], rs[4], psum[4];
      int exl = 0;
#pragma unroll
      for (int j = 0; j < 4; ++j) {
        const int row = rwD * 16 + l4 * 4 + j;
        const float cmb = fmaxf(pmb[row * 2], pmb[row * 2 + 1]);
        const bool ex = cmb > mreg[j] + 8.0f;
        const float mn = ex ? cmb : mreg[j];
        rs[j] = ex ? __expf(mreg[j] - mn) : 1.0f;
        p0[j] = __expf(s0[j] - mn);
        p1[j] = __expf(s1[j] - mn);
        psum[j] = p0[j] + p1[j];
        mreg[j] = mn;
        exl |= (int)ex;
      }
#pragma unroll
      for (int off = 1; off < 16; off <<= 1)
#pragma unroll
        for (int j = 0; j < 4; ++j) psum[j] += __shfl_xor(psum[j], off);
#pragma unroll
      for (int j = 0; j < 4; ++j) lreg[j] = lreg[j] * rs[j] + psum[j];
      const int exw = __any(exl);
      if (cwD == 0) {
        if (l15 == 0) {
#pragma unroll
          for (int j = 0; j < 4; ++j) resc[b * 64 + rwD * 16 + l4 * 4 + j] = rs[j];
        }
        if (lane == 0) flg[b * 4 + rwD] = exw ? 1u : 0u;
      }
      // P -> Ps[b] (bf16, XOR-swizzled stride 128)
      char* psb = PsB + b * 8192;
#pragma unroll
      for (int j = 0; j < 4; ++j) {
        const int row = rwD * 16 + l4 * 4 + j;
        const int sw = (row & 7) << 4;
        const int c0 = cwD * 32 + l15;
        *(u16*)(psb + row * 128 + ((c0 * 2) ^ sw)) = f2bf(p0[j]);
        *(u16*)(psb + row * 128 + (((c0 + 16) * 2) ^ sw)) = f2bf(p1[j]);
      }
    }

    // ---- PV(it-1): overlaps softmax-finish(it); wave = 64q x 64d, k=64 ----
    if (it > 0) {
      const int b1 = b ^ 1;
      const char* pr = PsB + b1 * 8192;
      uint4 fa = *(const uint4*)(flg + b1 * 4);
      if (fa.x | fa.y | fa.z | fa.w) {
#pragma unroll
        for (int fr = 0; fr < 4; ++fr) {
          f32x4 rf = *(const f32x4*)(resc + b1 * 64 + fr * 16 + l4 * 4);
#pragma unroll
          for (int cf = 0; cf < 4; ++cf)
#pragma unroll
            for (int j = 0; j < 4; ++j) o[fr][cf][j] *= rf[j];
        }
      }
#pragma unroll
      for (int s = 0; s < 2; ++s) {
        bf16x8 pa[4];
#pragma unroll
        for (int fr = 0; fr < 4; ++fr)
          pa[fr] = *(const bf16x8*)(pr + (fr * 16 + l15) * 128 +
                                    ((s * 64 + l4 * 16) ^ ((l15 & 7) << 4)));
#pragma unroll
        for (int fr = 0; fr < 4; ++fr)
#pragma unroll
          for (int cf = 0; cf < 4; ++cf)
            o[fr][cf] = __builtin_amdgcn_mfma_f32_16x16x32_bf16(
                pa[fr], *(const bf16x8*)&vreg[cf * 2 + s], o[fr][cf], 0, 0, 0);
      }
    }
  }

  // ---- publish l halves into pm buffer 0 (dead) ----
  if (l15 == 0) {
#pragma unroll
    for (int j = 0; j < 4; ++j) pm[(rwD * 16 + l4 * 4 + j) * 2 + cwD] = lreg[j];
  }
  __syncthreads();  // Ps(31)/resc(31)/flg(31)/l-halves visible

  // ---- tail PV(31) ----
  {
    uint4 vreg[8];
#pragma unroll
    for (int cf = 0; cf < 4; ++cf)
#pragma unroll
      for (int s = 0; s < 2; ++s)
        vreg[cf * 2 + s] = *(const uint4*)(Vtg +
            ((size_t)(bat * 512 + wid * 64 + cf * 16 + l15)) * 2048 +
            31 * 64 + s * 32 + l4 * 8);
    const char* pr = PsB + 8192;  // buffer 1 = 31&1
    uint4 fa = *(const uint4*)(flg + 4);
    if (fa.x | fa.y | fa.z | fa.w) {
#pragma unroll
      for (int fr = 0; fr < 4; ++fr) {
        f32x4 rf = *(const f32x4*)(resc + 64 + fr * 16 + l4 * 4);
#pragma unroll
        for (int cf = 0; cf < 4; ++cf)
#pragma unroll
          for (int j = 0; j < 4; ++j) o[fr][cf][j] *= rf[j];
      }
    }
#pragma unroll
    for (int s = 0; s < 2; ++s) {
      bf16x8 pa[4];
#pragma unroll
      for (int fr = 0; fr < 4; ++fr)
        pa[fr] = *(const bf16x8*)(pr + (fr * 16 + l15) * 128 +
                                  ((s * 64 + l4 * 16) ^ ((l15 & 7) << 4)));
#pragma unroll
      for (int fr = 0; fr < 4; ++fr)
#pragma unroll
        for (int cf = 0; cf < 4; ++cf)
          o[fr][cf] = __builtin_amdgcn_mfma_f32_16x16x32_bf16(
              pa[fr], *(const bf16x8*)&vreg[cf * 2 + s], o[fr][cf], 0, 0, 0);
    }
  }

  // ======== fused epilogue ========
  const float av = ap[0], bv = bp[0];
#pragma unroll
  for (int fr = 0; fr < 4; ++fr) {
#pragma unroll
    for (int j = 0; j < 4; ++j) {
      const int row = fr * 16 + l4 * 4 + j;
      const float2 lh = *(const float2*)(pm + row * 2);
      const float inv = 1.f / (lh.x + lh.y);
#pragma unroll
      for (int cf = 0; cf < 4; ++cf)
        o[fr][cf][j] = fmaxf(o[fr][cf][j] * inv, 0.f);  // o now holds R
    }
  }
  // write T = V - R into Ts (swizzled bf16, reuse Ks0; all waves past last use)
  {
    u16* Ts = Ks0;
#pragma unroll
    for (int fr = 0; fr < 4; ++fr)
#pragma unroll
      for (int cf = 0; cf < 4; ++cf) {
        const int col = wid * 64 + cf * 16 + l15;
#pragma unroll
        for (int j = 0; j < 4; ++j) {
          const int row = fr * 16 + l4 * 4 + j;
          float v = Vg[((size_t)(bat * 2048 + q0 + row)) * 512 + col];
          u16 t = f2bf(v - o[fr][cf][j]);
          *(u16*)((char*)Ts + row * 1024 + ((col * 2) ^ ((row & 7) << 4))) = t;
        }
      }
  }
  __syncthreads();  // T tile complete

  // projection GEMM: wave owns 64q x 64o (o-cols wid*64..+64), k=512
  f32x4 c2[4][4];
#pragma unroll
  for (int a = 0; a < 4; ++a)
#pragma unroll
    for (int b = 0; b < 4; ++b) c2[a][b] = (f32x4){0.f, 0.f, 0.f, 0.f};
  {
    const u16* Ts = Ks0;
#pragma unroll
    for (int ks = 0; ks < 16; ++ks) {
      bf16x8 aT[4];
#pragma unroll
      for (int fr = 0; fr < 4; ++fr) {
        const int row = fr * 16 + l15;
        aT[fr] = *(const bf16x8*)((const char*)Ts + row * 1024 +
                                  ((ks * 64 + l4 * 16) ^ ((row & 7) << 4)));
      }
#pragma unroll
      for (int cf = 0; cf < 4; ++cf) {
        const int orow = wid * 64 + cf * 16 + l15;
        bf16x8 bw = *(const bf16x8*)(Wb + (size_t)orow * 512 + ks * 32 + l4 * 8);
#pragma unroll
        for (int fr = 0; fr < 4; ++fr)
          c2[fr][cf] = __builtin_amdgcn_mfma_f32_16x16x32_bf16(aT[fr], bw, c2[fr][cf], 0, 0, 0);
      }
    }
  }
  // combine + store
#pragma unroll
  for (int fr = 0; fr < 4; ++fr)
#pragma unroll
    for (int cf = 0; cf < 4; ++cf) {
      const int col = wid * 64 + cf * 16 + l15;
#pragma unroll
      for (int j = 0; j < 4; ++j) {
        const int row = fr * 16 + l4 * 4 + j;
        float c = fmaxf(c2[fr][cf][j], 0.f);
        Out[((size_t)(bat * 2048 + q0 + row)) * 512 + col] = av * o[fr][cf][j] + bv * c;
      }
    }
}

extern "C" void kernel_launch(void* const* d_in, const int* in_sizes, int n_in,
                              void* d_out, int out_size, void* d_ws, size_t ws_size,
                              hipStream_t stream) {
  const float* Q = (const float*)d_in[0];
  const float* K = (const float*)d_in[1];
  const float* V = (const float*)d_in[2];
  const float* W = (const float*)d_in[3];
  const float* sp = (const float*)d_in[4];
  const float* ap = (const float*)d_in[5];
  const float* bp = (const float*)d_in[6];
  float* out = (float*)d_out;

  const long long tEl = 8LL * 2048 * 512;  // 8388608 elems per tensor
  u16* Kb = (u16*)d_ws;
  u16* Vt = Kb + tEl;
  u16* Wb = Vt + tEl;

  cvt_bf16_kernel<<<4096, 256, 0, stream>>>(K, Kb, tEl / 8);
  cvt_bf16_kernel<<<128, 256, 0, stream>>>(W, Wb, (512LL * 512) / 8);
  transpose_v_kernel<<<dim3(32, 8, 8), 256, 0, stream>>>(V, Vt);

  hipFuncSetAttribute(reinterpret_cast<const void*>(attn_kernel),
                      hipFuncAttributeMaxDynamicSharedMemorySize, ATT_LDS);
  attn_kernel<<<dim3(8, 32), 512, ATT_LDS, stream>>>(Q, Kb, Vt, V, Wb, sp, ap, bp, out);
}

// Round 4
// 183.230 us; speedup vs baseline: 1.1616x; 1.1616x over previous
//
#include <hip/hip_runtime.h>

typedef __attribute__((ext_vector_type(8))) short bf16x8;
typedef __attribute__((ext_vector_type(4))) float f32x4;
typedef unsigned int u32;
typedef unsigned short u16;

__device__ __forceinline__ u16 f2bf(float f) {
  u32 u = __float_as_uint(f);
  u += 0x7fffu + ((u >> 16) & 1u);   // RNE
  return (u16)(u >> 16);
}
__device__ __forceinline__ u32 pack2(float a, float b) {
  return (u32)f2bf(a) | ((u32)f2bf(b) << 16);
}
__device__ __forceinline__ void gload_lds16(const void* g, void* l) {
  __builtin_amdgcn_global_load_lds(
      (const __attribute__((address_space(1))) u32*)g,
      (__attribute__((address_space(3))) u32*)l, 16, 0, 0);
}

// ---------------- pre-pass: f32 -> bf16 (K, W) ----------------
__global__ void cvt_bf16_kernel(const float* __restrict__ in, u16* __restrict__ out,
                                long long n8) {
  long long i = (long long)blockIdx.x * blockDim.x + threadIdx.x;
  if (i >= n8) return;
  const float4* p = (const float4*)in + i * 2;
  float4 a = p[0], b = p[1];
  uint4 o;
  o.x = pack2(a.x, a.y); o.y = pack2(a.z, a.w);
  o.z = pack2(b.x, b.y); o.w = pack2(b.z, b.w);
  ((uint4*)out)[i] = o;
}

// ---------------- pre-pass: V[b][n][d] -> Vt[b][d][n] (bf16) ----------------
__global__ __launch_bounds__(256)
void transpose_v_kernel(const float* __restrict__ V, u16* __restrict__ Vt) {
  __shared__ float tile[64][65];
  const int n0 = blockIdx.x * 64, d0 = blockIdx.y * 64, bat = blockIdx.z;
  const int t = threadIdx.x;
  const int rr = t >> 4, cc = (t & 15) * 4;
#pragma unroll
  for (int i = 0; i < 4; ++i) {
    int r = i * 16 + rr;
    float4 v = *(const float4*)(V + ((size_t)(bat * 2048 + n0 + r)) * 512 + d0 + cc);
    tile[r][cc + 0] = v.x; tile[r][cc + 1] = v.y;
    tile[r][cc + 2] = v.z; tile[r][cc + 3] = v.w;
  }
  __syncthreads();
#pragma unroll
  for (int i = 0; i < 4; ++i) {
    int dr = i * 16 + rr;
    uint2 o;
    o.x = pack2(tile[cc + 0][dr], tile[cc + 1][dr]);
    o.y = pack2(tile[cc + 2][dr], tile[cc + 3][dr]);
    *(uint2*)(Vt + ((size_t)(bat * 512 + d0 + dr)) * 2048 + n0 + cc) = o;
  }
}

// ------- fused flash attention + projection (rotated, branchless phase A):
//   R = relu(softmax(QK^T*s) @ V);  Out = a*R + b*relu((V-R) @ W^T)
// Per iter it: [V(it-1) loads, K(it+1) DMA, sched_barrier,
//               QK^T(it) + PV(it-1) in ONE basic block] -> bar1 ->
//              softmax(it) -> bar2
// Rescale is UNCONDITIONAL (resc[row]==1.0f when no new max) -> no branch, no flg.
// LDS layout (bytes):
//  Ks0 [64][512] bf16 XOR-swz  @0       (65536)   (Q scratch in prologue; T=V-R in epilogue)
//  Ks1 [64][512] bf16 XOR-swz  @65536   (65536)
//  Ss  [64][68]  f32           @131072  (17408)
//  Ps  [64][..144B] bf16       @148480  (9216)
//  mrow/lrow/resc f32[64]      @158720/158976/159232
#define ATT_LDS 159552

__global__ __launch_bounds__(512, 2)
void attn_kernel(const float* __restrict__ Qf, const u16* __restrict__ Kb,
                 const u16* __restrict__ Vtg, const float* __restrict__ Vg,
                 const u16* __restrict__ Wb, const float* __restrict__ sp,
                 const float* __restrict__ ap, const float* __restrict__ bp,
                 float* __restrict__ Out) {
  extern __shared__ char smem[];
  u16* Ks0 = (u16*)smem;
  u16* Ks1 = (u16*)(smem + 65536);
  float* Ss = (float*)(smem + 131072);
  u16* Ps = (u16*)(smem + 148480);
  float* mrow = (float*)(smem + 158720);
  float* lrow = (float*)(smem + 158976);
  float* resc = (float*)(smem + 159232);

  const int tid = threadIdx.x, lane = tid & 63, wid = tid >> 6;
  const int bat = blockIdx.x, q0 = blockIdx.y * 64;  // flat%8 == bat -> per-XCD batch locality
  const float scale = sp[0] * 0.04419417382415922f;  // 1/sqrt(512)
  const int l15 = lane & 15, l4 = lane >> 4;
  const int srow = tid >> 3, sseg = tid & 7;
  const int rwD = wid >> 1, cwD = wid & 1;  // QK^T wave tile: 16 q-rows x 32 kv-cols

  // ---- prologue: stage Q (pre-scaled) f32 -> bf16 swizzled into Ks0 scratch ----
  {
    const float* qsrc = Qf + ((size_t)(bat * 2048 + q0 + srow)) * 512;
    char* qdst = (char*)Ks0 + srow * 1024;
    const int sw = (srow & 7) << 4;
#pragma unroll
    for (int j = 0; j < 8; ++j) {
      int sc = sseg * 8 + j;
      float4 x0 = *(const float4*)(qsrc + sc * 8);
      float4 x1 = *(const float4*)(qsrc + sc * 8 + 4);
      uint4 w;
      w.x = pack2(x0.x * scale, x0.y * scale); w.y = pack2(x0.z * scale, x0.w * scale);
      w.z = pack2(x1.x * scale, x1.y * scale); w.w = pack2(x1.z * scale, x1.w * scale);
      *(uint4*)(qdst + ((sc * 16) ^ sw)) = w;
    }
  }
  __syncthreads();

  // ---- load persistent Q A-fragments (16 q-rows per wave -> qf = 64 VGPRs) ----
  bf16x8 qf[16];
  {
    const char* qb = (const char*)Ks0 + (rwD * 16 + l15) * 1024;
    const int swA = (l15 & 7) << 4;
#pragma unroll
    for (int ks = 0; ks < 16; ++ks)
      qf[ks] = *(const bf16x8*)(qb + ((ks * 64 + l4 * 16) ^ swA));
  }
  __syncthreads();  // frag reads done before K(0) overwrites Ks0 scratch

  // ---- helpers (inlined lambdas; all loops fully unrolled, indices static) ----
  auto stage_k = [&](int kv1, u16* Knxt) {
#pragma unroll
    for (int j = 0; j < 8; ++j) {
      int row = wid * 8 + j;
      gload_lds16(Kb + ((size_t)(bat * 2048 + kv1 + row)) * 512 + ((lane ^ (row & 7)) * 8),
                  (char*)Knxt + row * 1024);
    }
  };
  auto load_v = [&](int itv, uint4* vreg) {
#pragma unroll
    for (int cf = 0; cf < 4; ++cf)
#pragma unroll
      for (int s = 0; s < 2; ++s)
        vreg[cf * 2 + s] = *(const uint4*)(Vtg +
            ((size_t)(bat * 512 + wid * 64 + cf * 16 + l15)) * 2048 +
            itv * 64 + s * 32 + l4 * 8);
  };

  const int swB = (l15 & 7) << 4;

  f32x4 o[4][4];
#pragma unroll
  for (int a = 0; a < 4; ++a)
#pragma unroll
    for (int b = 0; b < 4; ++b) o[a][b] = (f32x4){0.f, 0.f, 0.f, 0.f};

  auto qkt_step = [&](const u16* Kcur) {
    f32x4 s0 = (f32x4){0.f, 0.f, 0.f, 0.f};
    f32x4 s1 = (f32x4){0.f, 0.f, 0.f, 0.f};
    const char* kb0 = (const char*)Kcur + (cwD * 32 + l15) * 1024;
    const char* kb1 = kb0 + 16 * 1024;
#pragma unroll
    for (int ks = 0; ks < 16; ++ks) {
      const int off = (ks * 64 + l4 * 16) ^ swB;
      bf16x8 b0 = *(const bf16x8*)(kb0 + off);
      bf16x8 b1 = *(const bf16x8*)(kb1 + off);
      s0 = __builtin_amdgcn_mfma_f32_16x16x32_bf16(qf[ks], b0, s0, 0, 0, 0);
      s1 = __builtin_amdgcn_mfma_f32_16x16x32_bf16(qf[ks], b1, s1, 0, 0, 0);
    }
    const int r0 = rwD * 16 + l4 * 4;
    const int c0 = cwD * 32 + l15;
#pragma unroll
    for (int j = 0; j < 4; ++j) {
      Ss[(r0 + j) * 68 + c0] = s0[j];
      Ss[(r0 + j) * 68 + c0 + 16] = s1[j];
    }
  };

  auto pv_step = [&](const uint4* vreg) {
    // unconditional rescale: resc[row] == 1.0f when no new max (multiply is a no-op)
#pragma unroll
    for (int fr = 0; fr < 4; ++fr) {
      f32x4 rf = *(const f32x4*)(resc + fr * 16 + l4 * 4);
#pragma unroll
      for (int cf = 0; cf < 4; ++cf)
#pragma unroll
        for (int j = 0; j < 4; ++j) o[fr][cf][j] *= rf[j];
    }
#pragma unroll
    for (int s = 0; s < 2; ++s) {
      bf16x8 pa[4];
#pragma unroll
      for (int fr = 0; fr < 4; ++fr)
        pa[fr] = *(const bf16x8*)((const char*)Ps + (fr * 16 + l15) * 144 + s * 64 + l4 * 16);
#pragma unroll
      for (int fr = 0; fr < 4; ++fr)
#pragma unroll
        for (int cf = 0; cf < 4; ++cf)
          o[fr][cf] = __builtin_amdgcn_mfma_f32_16x16x32_bf16(
              pa[fr], *(const bf16x8*)&vreg[cf * 2 + s], o[fr][cf], 0, 0, 0);
    }
  };

  auto softmax_step = [&]() {
    const int row = srow, g = sseg;
    float4 sv0 = *(const float4*)(Ss + row * 68 + g * 8);
    float4 sv1 = *(const float4*)(Ss + row * 68 + g * 8 + 4);
    float mt = fmaxf(fmaxf(fmaxf(sv0.x, sv0.y), fmaxf(sv0.z, sv0.w)),
                     fmaxf(fmaxf(sv1.x, sv1.y), fmaxf(sv1.z, sv1.w)));
#pragma unroll
    for (int off = 1; off < 8; off <<= 1) mt = fmaxf(mt, __shfl_xor(mt, off));
    const float mold = mrow[row];
    const bool exceed = (mt > mold + 8.0f);
    const float mnew = exceed ? mt : mold;  // deferred max; P bounded by e^8
    float p0 = __expf(sv0.x - mnew), p1 = __expf(sv0.y - mnew);
    float p2 = __expf(sv0.z - mnew), p3 = __expf(sv0.w - mnew);
    float p4 = __expf(sv1.x - mnew), p5 = __expf(sv1.y - mnew);
    float p6 = __expf(sv1.z - mnew), p7 = __expf(sv1.w - mnew);
    float ps = ((p0 + p1) + (p2 + p3)) + ((p4 + p5) + (p6 + p7));
#pragma unroll
    for (int off = 1; off < 8; off <<= 1) ps += __shfl_xor(ps, off);
    if (g == 0) {
      float rs = exceed ? __expf(mold - mnew) : 1.0f;
      resc[row] = rs;
      lrow[row] = lrow[row] * rs + ps;
      mrow[row] = mnew;
    }
    uint4 pw;
    pw.x = pack2(p0, p1); pw.y = pack2(p2, p3);
    pw.z = pack2(p4, p5); pw.w = pack2(p6, p7);
    *(uint4*)((char*)Ps + row * 144 + g * 16) = pw;
  };

  // ---- stage K(0) via global_load_lds (source pre-swizzled per lane) ----
  stage_k(0, Ks0);
  if (tid < 64) { mrow[tid] = -1e30f; lrow[tid] = 0.f; }
  __syncthreads();  // K(0) resident + visible (drains DMA)

  // ---- peeled iteration 0: no PV yet ----
  stage_k(64, Ks1);                      // K(1) -> Ks1
  __builtin_amdgcn_sched_barrier(0);
  qkt_step(Ks0);
  __syncthreads();  // bar1(0): Ss visible; K(1) drained
  softmax_step();
  __syncthreads();  // bar2(0): Ps/resc visible

  // ---- main loop: QK^T(it) and PV(it-1) fused in one scheduling region ----
  for (int it = 1; it < 32; ++it) {
    const u16* Kcur = (it & 1) ? Ks1 : Ks0;
    u16* Knxt = (it & 1) ? Ks0 : Ks1;

    uint4 vreg[8];
    load_v(it - 1, vreg);                // V for PV(it-1), JIT (cover = QK^T)
    if (it < 31) stage_k((it + 1) * 64, Knxt);  // drains at bar1(it)
    __builtin_amdgcn_sched_barrier(0);   // pin load issues above compute

    qkt_step(Kcur);                      // writes Ss(it)
    pv_step(vreg);                       // reads Ps/resc of (it-1); same BB as QK^T

    __syncthreads();  // bar1: Ss visible; DMA/V drained; PV's Ps reads complete
    softmax_step();   // reads Ss(it), writes Ps/resc(it)
    __syncthreads();  // bar2
  }

  // ---- tail PV(31) ----
  {
    uint4 vreg[8];
    load_v(31, vreg);
    pv_step(vreg);
  }

  // ======== fused epilogue ========
  // R = relu(O/l) in regs; T = V-R -> Ts (bf16, swizzled, reuse Ks0);
  // C = T @ W^T; Out = a*R + b*relu(C)
  const float av = ap[0], bv = bp[0];
#pragma unroll
  for (int fr = 0; fr < 4; ++fr) {
    f32x4 lv = *(const f32x4*)(lrow + fr * 16 + l4 * 4);
    f32x4 inv;
#pragma unroll
    for (int j = 0; j < 4; ++j) inv[j] = 1.f / lv[j];
#pragma unroll
    for (int cf = 0; cf < 4; ++cf)
#pragma unroll
      for (int j = 0; j < 4; ++j)
        o[fr][cf][j] = fmaxf(o[fr][cf][j] * inv[j], 0.f);  // o now holds R
  }
  // write T = V - R into Ts (swizzled bf16). All waves past last Ks0 read: safe.
  {
    u16* Ts = Ks0;
#pragma unroll
    for (int fr = 0; fr < 4; ++fr)
#pragma unroll
      for (int cf = 0; cf < 4; ++cf) {
        const int col = wid * 64 + cf * 16 + l15;
#pragma unroll
        for (int j = 0; j < 4; ++j) {
          const int row = fr * 16 + l4 * 4 + j;
          float v = Vg[((size_t)(bat * 2048 + q0 + row)) * 512 + col];
          u16 t = f2bf(v - o[fr][cf][j]);
          *(u16*)((char*)Ts + row * 1024 + ((col * 2) ^ ((row & 7) << 4))) = t;
        }
      }
  }
  __syncthreads();  // T tile complete

  // projection GEMM: wave owns 64q x 64o (o-cols wid*64..+64), k=512
  f32x4 c2[4][4];
#pragma unroll
  for (int a = 0; a < 4; ++a)
#pragma unroll
    for (int b = 0; b < 4; ++b) c2[a][b] = (f32x4){0.f, 0.f, 0.f, 0.f};
  {
    const u16* Ts = Ks0;
#pragma unroll
    for (int ks = 0; ks < 16; ++ks) {
      bf16x8 aT[4];
#pragma unroll
      for (int fr = 0; fr < 4; ++fr) {
        const int row = fr * 16 + l15;
        aT[fr] = *(const bf16x8*)((const char*)Ts + row * 1024 +
                                  ((ks * 64 + l4 * 16) ^ ((row & 7) << 4)));
      }
#pragma unroll
      for (int cf = 0; cf < 4; ++cf) {
        const int orow = wid * 64 + cf * 16 + l15;
        bf16x8 bw = *(const bf16x8*)(Wb + (size_t)orow * 512 + ks * 32 + l4 * 8);
#pragma unroll
        for (int fr = 0; fr < 4; ++fr)
          c2[fr][cf] = __builtin_amdgcn_mfma_f32_16x16x32_bf16(aT[fr], bw, c2[fr][cf], 0, 0, 0);
      }
    }
  }
  // combine + store
#pragma unroll
  for (int fr = 0; fr < 4; ++fr)
#pragma unroll
    for (int cf = 0; cf < 4; ++cf) {
      const int col = wid * 64 + cf * 16 + l15;
#pragma unroll
      for (int j = 0; j < 4; ++j) {
        const int row = fr * 16 + l4 * 4 + j;
        float c = fmaxf(c2[fr][cf][j], 0.f);
        Out[((size_t)(bat * 2048 + q0 + row)) * 512 + col] = av * o[fr][cf][j] + bv * c;
      }
    }
}

extern "C" void kernel_launch(void* const* d_in, const int* in_sizes, int n_in,
                              void* d_out, int out_size, void* d_ws, size_t ws_size,
                              hipStream_t stream) {
  const float* Q = (const float*)d_in[0];
  const float* K = (const float*)d_in[1];
  const float* V = (const float*)d_in[2];
  const float* W = (const float*)d_in[3];
  const float* sp = (const float*)d_in[4];
  const float* ap = (const float*)d_in[5];
  const float* bp = (const float*)d_in[6];
  float* out = (float*)d_out;

  const long long tEl = 8LL * 2048 * 512;  // 8388608 elems per tensor
  u16* Kb = (u16*)d_ws;
  u16* Vt = Kb + tEl;
  u16* Wb = Vt + tEl;

  cvt_bf16_kernel<<<4096, 256, 0, stream>>>(K, Kb, tEl / 8);
  cvt_bf16_kernel<<<128, 256, 0, stream>>>(W, Wb, (512LL * 512) / 8);
  transpose_v_kernel<<<dim3(32, 8, 8), 256, 0, stream>>>(V, Vt);

  hipFuncSetAttribute(reinterpret_cast<const void*>(attn_kernel),
                      hipFuncAttributeMaxDynamicSharedMemorySize, ATT_LDS);
  attn_kernel<<<dim3(8, 32), 512, ATT_LDS, stream>>>(Q, Kb, Vt, V, Wb, sp, ap, bp, out);
}